// Round 8
// baseline (227.410 us; speedup 1.0000x reference)
//
#include <hip/hip_runtime.h>
#include <hip/hip_bf16.h>
#include <stdint.h>

typedef __bf16 bf16x8 __attribute__((ext_vector_type(8)));
typedef float  f32x4  __attribute__((ext_vector_type(4)));

#define NROWS   8192
#define DIMK    128
#define RECON_N 6422528
#define RECON_BLOCKS 1568            // x256 thr x4 float4 rounds
#define NTILES  528                  // 32x32 upper-tri grid of 256x256 tiles
#define K1_BLOCKS 2592               // 1024 prep + 1568 recon
#define K2_BLOCKS 1040               // 528 sim + 512 group

// workspace layout (float offsets)
#define WS_RS     0                  // rowSum[8192], atomic-accumulated
#define WS_G      8192
#define WS_E      16384
#define WS_RPART  24576              // 1568 recon partials
#define WS_DPART  26144              // 512 group partials
#define WS_PB     26656              // byte 106624 (16B aligned); bf16 P, 2MB

__device__ __forceinline__ void async16(const void* g, void* l) {
    __builtin_amdgcn_global_load_lds(
        (const __attribute__((address_space(1))) void*)g,
        (__attribute__((address_space(3))) void*)l, 16, 0, 0);
}

__device__ __forceinline__ unsigned short f2bf(float f) {
    union { __hip_bfloat16 h; unsigned short u; } v;
    v.h = __float2bfloat16(f);
    return v.u;
}

// -------- k1: streaming kernel — prep (P fp32->bf16, zero RS) + recon -------
__global__ __launch_bounds__(256) void stream_kernel(
        const float4* __restrict__ Pf,
        uint2* __restrict__ Pb,
        const float4* __restrict__ X,
        const float4* __restrict__ Y,
        float* __restrict__ ws) {
    __shared__ float red[4];
    const int bid = blockIdx.x;
    const int wave = threadIdx.x >> 6, lane = threadIdx.x & 63;

    if (bid < 1024) {
        // ---- prep: convert P, zero RS ----
        int idx = bid * 256 + threadIdx.x;       // 262144 float4s
        if (bid < 32) ws[WS_RS + idx] = 0.f;     // rowSum[8192] = 0
        float4 a = Pf[idx];
        uint2 r;
        r.x = (uint32_t)f2bf(a.x) | ((uint32_t)f2bf(a.y) << 16);
        r.y = (uint32_t)f2bf(a.z) | ((uint32_t)f2bf(a.w) << 16);
        Pb[idx] = r;
        return;
    }

    // ---- recon ----
    const int idx = bid - 1024;
    int base = idx * 1024 + threadIdx.x;
    float4 a0 = X[base],       b0 = Y[base];
    float4 a1 = X[base + 256], b1 = Y[base + 256];
    float4 a2 = X[base + 512], b2 = Y[base + 512];
    float4 a3 = X[base + 768], b3 = Y[base + 768];
    float s = 0.f, d;
    d = a0.x - b0.x; s += d * d;  d = a0.y - b0.y; s += d * d;
    d = a0.z - b0.z; s += d * d;  d = a0.w - b0.w; s += d * d;
    d = a1.x - b1.x; s += d * d;  d = a1.y - b1.y; s += d * d;
    d = a1.z - b1.z; s += d * d;  d = a1.w - b1.w; s += d * d;
    d = a2.x - b2.x; s += d * d;  d = a2.y - b2.y; s += d * d;
    d = a2.z - b2.z; s += d * d;  d = a2.w - b2.w; s += d * d;
    d = a3.x - b3.x; s += d * d;  d = a3.y - b3.y; s += d * d;
    d = a3.z - b3.z; s += d * d;  d = a3.w - b3.w; s += d * d;
#pragma unroll
    for (int mm = 1; mm < 64; mm <<= 1) s += __shfl_xor(s, mm, 64);
    if (lane == 0) red[wave] = s;
    __syncthreads();
    if (threadIdx.x == 0)
        ws[WS_RPART + idx] = red[0] + red[1] + red[2] + red[3];
}

// -------- k2: sim (256x256 symmetric tiles) + group --------
// Tile (I,J), I<=J over 32 slabs of 256 rows. Each of 4 waves owns 64 rows.
// B staged per 128-col chunk (2 chunks); rowAcc accumulates across chunks;
// col-sums (off-diag) per chunk via cred + symmetry. Traffic: 66 MB total.
__global__ __launch_bounds__(256, 3) void sim_kernel(
        const unsigned short* __restrict__ Pb,
        const float* __restrict__ Pf,
        float* __restrict__ ws) {
    __shared__ unsigned short tile[128 * 128];   // 32 KB (B chunk staging)
    __shared__ float sred[4][64];                // row sums [wave][row]
    __shared__ float cred[4][128];               // col partials [wave][col]
    __shared__ float dred[4];                    // group partials
    const int bx = blockIdx.x;
    const int wave = threadIdx.x >> 6, lane = threadIdx.x & 63;

    int role, idx;                               // 0=sim 1=group
    if (bx < 1024) { role = bx & 1; idx = bx >> 1; }
    else           { role = 0; idx = 512 + (bx - 1024); }   // sim 512..527

    if (role == 0) {
        float* RS = ws + WS_RS;
        // decode u -> (I,J) over 32-slab upper triangle: base(I)=32I-I(I-1)/2
        float ff = 32.5f - sqrtf(1056.25f - 2.0f * (float)idx);
        int I = (int)ff;
        int base = 32 * I - (I * (I - 1)) / 2;
        if (idx < base) { --I; base = 32 * I - (I * (I - 1)) / 2; }
        else { int nb = 32 * (I + 1) - ((I + 1) * I) / 2;
               if (idx >= nb) { ++I; base = nb; } }
        const int J = I + (idx - base);

        const int m = lane & 15, kq = lane >> 4;
        const int wr = wave;

        // stage B chunk 0 = rows J*256..+128, swizzled (r,q)->(r,(q+r)&15)
        {
            const char* gB = (const char*)(Pb + (size_t)(J * 256) * DIMK);
#pragma unroll
            for (int i = 0; i < 8; ++i) {
                int chunk = i * 256 + threadIdx.x;       // 2048 x 16B
                int r = chunk >> 4, qp = chunk & 15;
                async16(gB + r * 256 + (((qp - r) & 15) << 4),
                        (char*)tile + chunk * 16);
            }
        }

        // A fragments: wave's 64 rows of the 256-row I-slab (L2-hot)
        bf16x8 Af[4][4];
        const unsigned short* gA = Pb + (size_t)(I * 256 + wr * 64) * DIMK;
#pragma unroll
        for (int i = 0; i < 4; ++i) {
            const unsigned short* rowp = gA + (size_t)(i * 16 + m) * DIMK + kq * 8;
#pragma unroll
            for (int kk = 0; kk < 4; ++kk)
                Af[i][kk] = *(const bf16x8*)(rowp + kk * 32);
        }

        float rowAcc[4][4];
#pragma unroll
        for (int i = 0; i < 4; ++i)
#pragma unroll
            for (int r = 0; r < 4; ++r) rowAcc[i][r] = 0.f;

#pragma unroll
        for (int c = 0; c < 2; ++c) {
            __syncthreads();                     // drain stage (+Af on c=0)

            float colAcc[8];
#pragma unroll
            for (int j = 0; j < 8; ++j) {
                int rl = j * 16 + m;
                bf16x8 Bf[4];
#pragma unroll
                for (int kk = 0; kk < 4; ++kk)
                    Bf[kk] = *(const bf16x8*)((const char*)tile + rl * 256 +
                                              (((kq + kk * 4 + rl) & 15) << 4));
                f32x4 acc[4];
#pragma unroll
                for (int i = 0; i < 4; ++i) acc[i] = (f32x4){0.f, 0.f, 0.f, 0.f};
#pragma unroll
                for (int kk = 0; kk < 4; ++kk)
#pragma unroll
                    for (int i = 0; i < 4; ++i)
                        acc[i] = __builtin_amdgcn_mfma_f32_16x16x32_bf16(
                            Af[i][kk], Bf[kk], acc[i], 0, 0, 0);
                float cs = 0.f;
#pragma unroll
                for (int i = 0; i < 4; ++i)
#pragma unroll
                    for (int r = 0; r < 4; ++r) {
                        float e = __builtin_amdgcn_exp2f(acc[i][r] * 14.426950408889634f);
                        rowAcc[i][r] += e;
                        cs += e;
                    }
                cs += __shfl_xor(cs, 16, 64);    // sum over kq groups
                cs += __shfl_xor(cs, 32, 64);
                colAcc[j] = cs;                  // col sum over wave's 64 rows
            }
            if (kq == 0) {
#pragma unroll
                for (int j = 0; j < 8; ++j)
                    cred[wr][j * 16 + m] = colAcc[j];
            }
            __syncthreads();                     // tile free + cred ready
            if (c == 0) {
                // stage B chunk 1 (overlaps col atomics)
                const char* gB = (const char*)(Pb + (size_t)(J * 256 + 128) * DIMK);
#pragma unroll
                for (int i = 0; i < 8; ++i) {
                    int chunk = i * 256 + threadIdx.x;
                    int r = chunk >> 4, qp = chunk & 15;
                    async16(gB + r * 256 + (((qp - r) & 15) << 4),
                            (char*)tile + chunk * 16);
                }
            }
            if (I != J && wave < 2) {
                int col = wave * 64 + lane;
                float v = cred[0][col] + cred[1][col] + cred[2][col] + cred[3][col];
                atomicAdd(&RS[J * 256 + c * 128 + col], v);
            }
        }

        // row-sums: reduce over 16 cols (m), publish via sred, one atomic/row
#pragma unroll
        for (int i = 0; i < 4; ++i)
#pragma unroll
            for (int r = 0; r < 4; ++r) {
                float sv = rowAcc[i][r];
                sv += __shfl_xor(sv, 1, 64);
                sv += __shfl_xor(sv, 2, 64);
                sv += __shfl_xor(sv, 4, 64);
                sv += __shfl_xor(sv, 8, 64);
                rowAcc[i][r] = sv;
            }
        if (m == 0) {
#pragma unroll
            for (int i = 0; i < 4; ++i)
#pragma unroll
                for (int r = 0; r < 4; ++r)
                    sred[wr][i * 16 + kq * 4 + r] = rowAcc[i][r];
        }
        __syncthreads();
        atomicAdd(&RS[I * 256 + wr * 64 + lane], sred[wr][lane]);
    } else {
        // ---------------- group ----------------
        float* G = ws + WS_G;
        float* E = ws + WS_E;
        int g = idx * 4 + wave;
        const float* base = Pf + (size_t)g * 4 * DIMK;
        float v[4][2];
#pragma unroll
        for (int r = 0; r < 4; ++r) {
            v[r][0] = base[r * DIMK + lane];
            v[r][1] = base[r * DIMK + 64 + lane];
        }
        float dmat[4][4];
#pragma unroll
        for (int r = 0; r < 4; ++r)
#pragma unroll
            for (int s2 = r; s2 < 4; ++s2) {
                float p = v[r][0] * v[s2][0] + v[r][1] * v[s2][1];
#pragma unroll
                for (int mm = 1; mm < 64; mm <<= 1) p += __shfl_xor(p, mm, 64);
                dmat[r][s2] = p; dmat[s2][r] = p;
            }
        if (lane == 0) {
            float distp = 0.f;
#pragma unroll
            for (int r = 0; r < 4; ++r)
#pragma unroll
                for (int s2 = r + 1; s2 < 4; ++s2)
                    distp += dmat[r][r] + dmat[s2][s2] - 2.f * dmat[r][s2];
            dred[wave] = distp;
#pragma unroll
            for (int r = 0; r < 4; ++r) {
                float Gs = 0.f, Es = 0.f;
#pragma unroll
                for (int s2 = 0; s2 < 4; ++s2) {
                    float sim = dmat[r][s2] * 10.0f;
                    float e = __expf(sim);
                    Gs += e;
                    if (sim == 1.0f) Es += e;
                }
                G[g * 4 + r] = Gs;
                E[g * 4 + r] = Es;
            }
        }
        __syncthreads();
        if (threadIdx.x == 0)
            ws[WS_DPART + idx] = dred[0] + dred[1] + dred[2] + dred[3];
    }
}

// -------- k3: finalize — one 1024-thread block --------
__global__ __launch_bounds__(1024) void finalize_kernel(const float* __restrict__ ws,
                                                        float* __restrict__ out) {
    __shared__ float redc[16], redr[16], redd[16];
    const float* RS = ws + WS_RS;
    const float* G  = ws + WS_G;
    const float* E  = ws + WS_E;

    float c = 0.f;
    for (int r = threadIdx.x; r < NROWS; r += 1024) {
        float Sv = RS[r];
        c += __logf(Sv - E[r]) - __logf(G[r] - E[r]);
    }
    float rs = 0.f;
    for (int i = threadIdx.x; i < RECON_BLOCKS; i += 1024) rs += ws[WS_RPART + i];
    float ds = 0.f;
    for (int i = threadIdx.x; i < 512; i += 1024) ds += ws[WS_DPART + i];

#pragma unroll
    for (int mm = 1; mm < 64; mm <<= 1) {
        c  += __shfl_xor(c,  mm, 64);
        rs += __shfl_xor(rs, mm, 64);
        ds += __shfl_xor(ds, mm, 64);
    }
    int wave = threadIdx.x >> 6, lane = threadIdx.x & 63;
    if (lane == 0) { redc[wave] = c; redr[wave] = rs; redd[wave] = ds; }
    __syncthreads();
    if (threadIdx.x == 0) {
        float cs = 0.f, rss = 0.f, dss = 0.f;
#pragma unroll
        for (int i = 0; i < 16; ++i) { cs += redc[i]; rss += redr[i]; dss += redd[i]; }
        float closs = cs / (float)NROWS;
        float recon = rss / (float)RECON_N;
        float dist  = dss / (float)(2048 * 6 * DIMK);
        out[0] = recon + closs + dist;
        out[1] = closs;
        out[2] = recon;
        out[3] = dist;
    }
}

extern "C" void kernel_launch(void* const* d_in, const int* in_sizes, int n_in,
                              void* d_out, int out_size, void* d_ws, size_t ws_size,
                              hipStream_t stream) {
    const float* P  = (const float*)d_in[0];    // projections 8192x128 fp32
    const float4* X = (const float4*)d_in[1];   // xrecon 8192x784 fp32
    const float4* Y = (const float4*)d_in[2];   // recon_label fp32
    float* out = (float*)d_out;                 // 4 fp32 scalars
    float* w = (float*)d_ws;
    unsigned short* Pb = (unsigned short*)(w + WS_PB);

    stream_kernel<<<K1_BLOCKS, 256, 0, stream>>>((const float4*)P, (uint2*)Pb,
                                                 X, Y, w);
    sim_kernel<<<K2_BLOCKS, 256, 0, stream>>>(Pb, P, w);
    finalize_kernel<<<1, 1024, 0, stream>>>(w, out);
}

// Round 9
// 119.946 us; speedup vs baseline: 1.8959x; 1.8959x over previous
//
#include <hip/hip_runtime.h>
#include <hip/hip_bf16.h>
#include <stdint.h>

typedef __bf16 bf16x8 __attribute__((ext_vector_type(8)));
typedef float  f32x4  __attribute__((ext_vector_type(4)));

#define NROWS   8192
#define DIMK    128
#define RECON_N 6422528
#define RECON_BLOCKS 1568            // x256 thr x4 float4 rounds
#define GROUP_BLOCKS 512
#define NTILES  2080                 // upper-tri 64x64 grid of 128x128 tiles
#define K1_BLOCKS 2592               // 1024 prep + 1568 recon
#define K2_BLOCKS 2592               // 2080 sim + 512 group

// workspace layout (float offsets)
#define WS_RS     0                  // rowSum[8192], atomic-accumulated
#define WS_G      8192
#define WS_E      16384
#define WS_RPART  24576              // 1568 recon partials
#define WS_DPART  26144              // 512 group partials
#define WS_PB     26656              // byte 106624 (16B aligned); bf16 P, 2MB

__device__ __forceinline__ void async16(const void* g, void* l) {
    __builtin_amdgcn_global_load_lds(
        (const __attribute__((address_space(1))) void*)g,
        (__attribute__((address_space(3))) void*)l, 16, 0, 0);
}

__device__ __forceinline__ unsigned short f2bf(float f) {
    union { __hip_bfloat16 h; unsigned short u; } v;
    v.h = __float2bfloat16(f);
    return v.u;
}

// -------- k1: streaming kernel — prep (P fp32->bf16, zero RS) + recon -------
// No LDS tile -> high residency -> streams X/Y near HBM rate.
__global__ __launch_bounds__(256) void stream_kernel(
        const float4* __restrict__ Pf,
        uint2* __restrict__ Pb,
        const float4* __restrict__ X,
        const float4* __restrict__ Y,
        float* __restrict__ ws) {
    __shared__ float red[4];
    const int bid = blockIdx.x;
    const int wave = threadIdx.x >> 6, lane = threadIdx.x & 63;

    if (bid < 1024) {
        // ---- prep: convert P, zero RS ----
        int idx = bid * 256 + threadIdx.x;       // 262144 float4s
        if (bid < 32) ws[WS_RS + idx] = 0.f;     // rowSum[8192] = 0
        float4 a = Pf[idx];
        uint2 r;
        r.x = (uint32_t)f2bf(a.x) | ((uint32_t)f2bf(a.y) << 16);
        r.y = (uint32_t)f2bf(a.z) | ((uint32_t)f2bf(a.w) << 16);
        Pb[idx] = r;
        return;
    }

    // ---- recon ----
    const int idx = bid - 1024;
    int base = idx * 1024 + threadIdx.x;
    float4 a0 = X[base],       b0 = Y[base];
    float4 a1 = X[base + 256], b1 = Y[base + 256];
    float4 a2 = X[base + 512], b2 = Y[base + 512];
    float4 a3 = X[base + 768], b3 = Y[base + 768];
    float s = 0.f, d;
    d = a0.x - b0.x; s += d * d;  d = a0.y - b0.y; s += d * d;
    d = a0.z - b0.z; s += d * d;  d = a0.w - b0.w; s += d * d;
    d = a1.x - b1.x; s += d * d;  d = a1.y - b1.y; s += d * d;
    d = a1.z - b1.z; s += d * d;  d = a1.w - b1.w; s += d * d;
    d = a2.x - b2.x; s += d * d;  d = a2.y - b2.y; s += d * d;
    d = a2.z - b2.z; s += d * d;  d = a2.w - b2.w; s += d * d;
    d = a3.x - b3.x; s += d * d;  d = a3.y - b3.y; s += d * d;
    d = a3.z - b3.z; s += d * d;  d = a3.w - b3.w; s += d * d;
#pragma unroll
    for (int mm = 1; mm < 64; mm <<= 1) s += __shfl_xor(s, mm, 64);
    if (lane == 0) red[wave] = s;
    __syncthreads();
    if (threadIdx.x == 0)
        ws[WS_RPART + idx] = red[0] + red[1] + red[2] + red[3];
}

// -------- k2: compute kernel — sim (symmetric 128x128 tiles) + group --------
// XCD-aware bijective swizzle (2592 = 8 * 324): consecutive tiles share the
// A-slab of Pb; chunking them per-XCD makes those reads local-L2 hits.
__global__ __launch_bounds__(256, 3) void sim_kernel(
        const unsigned short* __restrict__ Pb,
        const float* __restrict__ Pf,
        float* __restrict__ ws) {
    __shared__ unsigned short tile[128 * 128];   // 32 KB (sim B staging)
    __shared__ float sred[2][2][64];             // row partials [wc][wr][row]
    __shared__ float cred[2][128];               // col partials [wr][col]
    __shared__ float dred[4];                    // group partials
    const int bx0 = blockIdx.x;
    const int bx = (bx0 & 7) * 324 + (bx0 >> 3); // bijective XCD swizzle
    const int wave = threadIdx.x >> 6, lane = threadIdx.x & 63;

    int role, idx;                               // 0=sim 1=group
    if (bx < 2560) {
        int r5 = bx % 5, c5 = bx / 5;
        if (r5 == 4) { role = 1; idx = c5; }
        else         { role = 0; idx = c5 * 4 + r5; }
    } else {
        role = 0; idx = 2048 + (bx - 2560);
    }

    if (role == 0) {
        float* RS = ws + WS_RS;
        // decode linear idx -> (I,J) upper triangle
        float ff = 64.5f - sqrtf(64.5f * 64.5f - 2.0f * (float)idx);
        int I = (int)ff;
        int base = I * 64 - (I * (I - 1)) / 2;
        if (idx < base) { --I; base = I * 64 - (I * (I - 1)) / 2; }
        else { int nb = (I + 1) * 64 - ((I + 1) * I) / 2;
               if (idx >= nb) { ++I; base = nb; } }
        const int J = I + (idx - base);

        const int wr = wave >> 1, wc = wave & 1;
        const int m = lane & 15, kq = lane >> 4;

        // stage B = J-block rows, swizzled (r,q)->(r,(q+r)&15), linear dest
        const char* gB = (const char*)(Pb + (size_t)J * 128 * DIMK);
#pragma unroll
        for (int i = 0; i < 8; ++i) {
            int chunk = i * 256 + wave * 64 + lane;      // 2048 x 16B
            int r = chunk >> 4, qp = chunk & 15;
            async16(gB + r * 256 + (((qp - r) & 15) << 4),
                    (char*)tile + chunk * 16);
        }

        // A fragments = I-block rows from global (L2-hot)
        bf16x8 Af[4][4];
        const unsigned short* gA = Pb + (size_t)(I * 128 + wr * 64) * DIMK;
#pragma unroll
        for (int i = 0; i < 4; ++i) {
            const unsigned short* rowp = gA + (size_t)(i * 16 + m) * DIMK + kq * 8;
#pragma unroll
            for (int kk = 0; kk < 4; ++kk)
                Af[i][kk] = *(const bf16x8*)(rowp + kk * 32);
        }

        float rowAcc[4][4];
        float colAcc[4];
#pragma unroll
        for (int i = 0; i < 4; ++i)
#pragma unroll
            for (int r = 0; r < 4; ++r) rowAcc[i][r] = 0.f;

        __syncthreads();                         // drain stage + Af

#pragma unroll
        for (int j = 0; j < 4; ++j) {
            int rl = wc * 64 + j * 16 + m;
            bf16x8 Bf[4];
#pragma unroll
            for (int kk = 0; kk < 4; ++kk)
                Bf[kk] = *(const bf16x8*)((const char*)tile + rl * 256 +
                                          (((kq + kk * 4 + rl) & 15) << 4));
            f32x4 acc[4];
#pragma unroll
            for (int i = 0; i < 4; ++i) acc[i] = (f32x4){0.f, 0.f, 0.f, 0.f};
#pragma unroll
            for (int kk = 0; kk < 4; ++kk)
#pragma unroll
                for (int i = 0; i < 4; ++i)
                    acc[i] = __builtin_amdgcn_mfma_f32_16x16x32_bf16(
                        Af[i][kk], Bf[kk], acc[i], 0, 0, 0);
            float cs = 0.f;
#pragma unroll
            for (int i = 0; i < 4; ++i)
#pragma unroll
                for (int r = 0; r < 4; ++r) {
                    float e = __builtin_amdgcn_exp2f(acc[i][r] * 14.426950408889634f);
                    rowAcc[i][r] += e;
                    cs += e;
                }
            cs += __shfl_xor(cs, 16, 64);        // sum over kq groups
            cs += __shfl_xor(cs, 32, 64);
            colAcc[j] = cs;                      // col sum over wave's 64 rows
        }

        // row-sums: reduce over 16 cols (m)
#pragma unroll
        for (int i = 0; i < 4; ++i)
#pragma unroll
            for (int r = 0; r < 4; ++r) {
                float sv = rowAcc[i][r];
                sv += __shfl_xor(sv, 1, 64);
                sv += __shfl_xor(sv, 2, 64);
                sv += __shfl_xor(sv, 4, 64);
                sv += __shfl_xor(sv, 8, 64);
                rowAcc[i][r] = sv;
            }
        if (m == 0) {
#pragma unroll
            for (int i = 0; i < 4; ++i)
#pragma unroll
                for (int r = 0; r < 4; ++r)
                    sred[wc][wr][i * 16 + kq * 4 + r] = rowAcc[i][r];
        }
        if (kq == 0) {
#pragma unroll
            for (int j = 0; j < 4; ++j)
                cred[wr][wc * 64 + j * 16 + m] = colAcc[j];
        }
        __syncthreads();
        if (wc == 0) {
            float v = sred[0][wr][lane] + sred[1][wr][lane];
            atomicAdd(&RS[I * 128 + wr * 64 + lane], v);
        } else if (I != J) {
            int col = wr * 64 + lane;
            float v = cred[0][col] + cred[1][col];
            atomicAdd(&RS[J * 128 + col], v);
        }
    } else {
        // ---------------- group ----------------
        float* G = ws + WS_G;
        float* E = ws + WS_E;
        int g = idx * 4 + wave;
        const float* base = Pf + (size_t)g * 4 * DIMK;
        float v[4][2];
#pragma unroll
        for (int r = 0; r < 4; ++r) {
            v[r][0] = base[r * DIMK + lane];
            v[r][1] = base[r * DIMK + 64 + lane];
        }
        float dmat[4][4];
#pragma unroll
        for (int r = 0; r < 4; ++r)
#pragma unroll
            for (int s2 = r; s2 < 4; ++s2) {
                float p = v[r][0] * v[s2][0] + v[r][1] * v[s2][1];
#pragma unroll
                for (int mm = 1; mm < 64; mm <<= 1) p += __shfl_xor(p, mm, 64);
                dmat[r][s2] = p; dmat[s2][r] = p;
            }
        if (lane == 0) {
            float distp = 0.f;
#pragma unroll
            for (int r = 0; r < 4; ++r)
#pragma unroll
                for (int s2 = r + 1; s2 < 4; ++s2)
                    distp += dmat[r][r] + dmat[s2][s2] - 2.f * dmat[r][s2];
            dred[wave] = distp;
#pragma unroll
            for (int r = 0; r < 4; ++r) {
                float Gs = 0.f, Es = 0.f;
#pragma unroll
                for (int s2 = 0; s2 < 4; ++s2) {
                    float sim = dmat[r][s2] * 10.0f;
                    float e = __expf(sim);
                    Gs += e;
                    if (sim == 1.0f) Es += e;
                }
                G[g * 4 + r] = Gs;
                E[g * 4 + r] = Es;
            }
        }
        __syncthreads();
        if (threadIdx.x == 0)
            ws[WS_DPART + idx] = dred[0] + dred[1] + dred[2] + dred[3];
    }
}

// -------- k3: finalize — one 1024-thread block --------
__global__ __launch_bounds__(1024) void finalize_kernel(const float* __restrict__ ws,
                                                        float* __restrict__ out) {
    __shared__ float redc[16], redr[16], redd[16];
    const float* RS = ws + WS_RS;
    const float* G  = ws + WS_G;
    const float* E  = ws + WS_E;

    float c = 0.f;
    for (int r = threadIdx.x; r < NROWS; r += 1024) {
        float Sv = RS[r];
        c += __logf(Sv - E[r]) - __logf(G[r] - E[r]);
    }
    float rs = 0.f;
    for (int i = threadIdx.x; i < RECON_BLOCKS; i += 1024) rs += ws[WS_RPART + i];
    float ds = 0.f;
    for (int i = threadIdx.x; i < GROUP_BLOCKS; i += 1024) ds += ws[WS_DPART + i];

#pragma unroll
    for (int mm = 1; mm < 64; mm <<= 1) {
        c  += __shfl_xor(c,  mm, 64);
        rs += __shfl_xor(rs, mm, 64);
        ds += __shfl_xor(ds, mm, 64);
    }
    int wave = threadIdx.x >> 6, lane = threadIdx.x & 63;
    if (lane == 0) { redc[wave] = c; redr[wave] = rs; redd[wave] = ds; }
    __syncthreads();
    if (threadIdx.x == 0) {
        float cs = 0.f, rss = 0.f, dss = 0.f;
#pragma unroll
        for (int i = 0; i < 16; ++i) { cs += redc[i]; rss += redr[i]; dss += redd[i]; }
        float closs = cs / (float)NROWS;
        float recon = rss / (float)RECON_N;
        float dist  = dss / (float)(2048 * 6 * DIMK);
        out[0] = recon + closs + dist;
        out[1] = closs;
        out[2] = recon;
        out[3] = dist;
    }
}

extern "C" void kernel_launch(void* const* d_in, const int* in_sizes, int n_in,
                              void* d_out, int out_size, void* d_ws, size_t ws_size,
                              hipStream_t stream) {
    const float* P  = (const float*)d_in[0];    // projections 8192x128 fp32
    const float4* X = (const float4*)d_in[1];   // xrecon 8192x784 fp32
    const float4* Y = (const float4*)d_in[2];   // recon_label fp32
    float* out = (float*)d_out;                 // 4 fp32 scalars
    float* w = (float*)d_ws;
    unsigned short* Pb = (unsigned short*)(w + WS_PB);

    stream_kernel<<<K1_BLOCKS, 256, 0, stream>>>((const float4*)P, (uint2*)Pb,
                                                 X, Y, w);
    sim_kernel<<<K2_BLOCKS, 256, 0, stream>>>(Pb, P, w);
    finalize_kernel<<<1, 1024, 0, stream>>>(w, out);
}